// Round 5
// baseline (504.450 us; speedup 1.0000x reference)
//
#include <hip/hip_runtime.h>
#include <hip/hip_bf16.h>
#include <math.h>

#define N_   1024
#define S_   256
#define D_   256
#define C_   256
#define R_   64
#define CLS_ 1000
#define INV16 0.0625f

typedef unsigned short ushortT;
typedef unsigned int uint32;
typedef short bf8 __attribute__((ext_vector_type(8)));
typedef float f4 __attribute__((ext_vector_type(4)));

static __device__ __forceinline__ float bf2f(uint32 u){
  return __uint_as_float(u << 16);
}
static __device__ __forceinline__ ushortT f2bf(float f){
  uint32 x = __float_as_uint(f);
  uint32 r = x + 0x7FFFu + ((x >> 16) & 1u);
  return (ushortT)(r >> 16);
}
static __device__ __forceinline__ uint32 packbf(float a, float b){
  return ((uint32)f2bf(b) << 16) | (uint32)f2bf(a);
}
static __device__ __forceinline__ float wred_max(float v){
  for (int o = 32; o; o >>= 1) v = fmaxf(v, __shfl_xor(v, o));
  return v;
}
static __device__ __forceinline__ float wred_sum(float v){
  for (int o = 32; o; o >>= 1) v += __shfl_xor(v, o);
  return v;
}
// swizzled byte offset inside a [rows][256]-bf16 LDS tile (row stride 512B)
static __device__ __forceinline__ int swz(int row, int colbyte){
  return row*512 + ((colbyte & ~15) ^ ((row & 7) << 4)) + (colbyte & 15);
}

// ---------------- K0: bf16 weight prep ----------------------------------------
__global__ __launch_bounds__(256) void k0(const float* __restrict__ cb,
    const float* __restrict__ rcb, const float* __restrict__ Wc,
    const float* __restrict__ Wr, ushortT* __restrict__ A1cat,
    ushortT* __restrict__ Wcr_bf)
{
  int t = blockIdx.x*256 + threadIdx.x;
  int stride = gridDim.x*256;
  for (int e = t; e < (C_ + R_)*D_; e += stride)
    A1cat[e] = f2bf(e < C_*D_ ? cb[e] : rcb[e - C_*D_]);
  for (int e = t; e < CLS_*D_; e += stride) Wcr_bf[e] = f2bf(Wc[e]);
  for (int e = t; e < D_*D_; e += stride)  Wcr_bf[CLS_*D_ + e] = f2bf(Wr[e]);
  for (int e = t; e < 24*D_; e += stride)  Wcr_bf[1256*D_ + e] = 0;
}

// ---------------- K0m: M = cb @ rcb^T, stored transposed MT[r][c] -------------
__global__ __launch_bounds__(256) void k0m(const float* __restrict__ cb,
    const float* __restrict__ rcb, float* __restrict__ MT_f32,
    ushortT* __restrict__ MT_bf)
{
  __shared__ float rl[D_];
  int r = blockIdx.x;        // 0..63
  int t = threadIdx.x;       // c = 0..255
  rl[t] = rcb[r*D_ + t];
  __syncthreads();
  float acc = 0.f;
  const float* crow = cb + t*D_;
  #pragma unroll 8
  for (int k = 0; k < D_; k += 4){
    float4 w = *(const float4*)(crow + k);
    acc += w.x*rl[k] + w.y*rl[k+1] + w.z*rl[k+2] + w.w*rl[k+3];
  }
  MT_f32[r*C_ + t] = acc;
  MT_bf[r*C_ + t]  = f2bf(acc);
}

// ---------------- K1: per-query pass ------------------------------------------
__global__ __launch_bounds__(256) void k1(const float* __restrict__ q,
    const float* __restrict__ cb, const float* __restrict__ rcb,
    const float* __restrict__ Wq, const float* __restrict__ MT_f32,
    float* __restrict__ cw_ws, float* __restrict__ rcw_ws)
{
  __shared__ float qv[D_], qp[D_], red[8], redB[8], cwl[C_];
  int n = blockIdx.x, t = threadIdx.x;
  qv[t] = q[n*D_ + t];
  __syncthreads();
  {
    float acc = 0.f;
    const float* wrow = Wq + t*D_;
    #pragma unroll 8
    for (int k = 0; k < D_; k += 4){
      float4 w = *(const float4*)(wrow + k);
      acc += qv[k]*w.x + qv[k+1]*w.y + qv[k+2]*w.z + qv[k+3]*w.w;
    }
    qp[t] = acc;
  }
  __syncthreads();
  float L = 0.f;
  {
    const float* crow = cb + t*D_;
    #pragma unroll 8
    for (int k = 0; k < D_; k += 4){
      float4 w = *(const float4*)(crow + k);
      L += qp[k]*w.x + qp[k+1]*w.y + qp[k+2]*w.z + qp[k+3]*w.w;
    }
    L *= INV16;
  }
  float m = wred_max(L);
  if ((t & 63) == 0) red[t >> 6] = m;
  __syncthreads();
  m = fmaxf(fmaxf(red[0], red[1]), fmaxf(red[2], red[3]));
  float e = __expf(L - m);
  float s = wred_sum(e);
  if ((t & 63) == 0) redB[t >> 6] = s;
  __syncthreads();
  s = redB[0] + redB[1] + redB[2] + redB[3];
  float w = e / s;
  cwl[t] = w;
  cw_ws[n*C_ + t] = w;
  __syncthreads();
  // rcw logits = (qp . rcb[r] - cw . MT[r]) / 16   (M-decomposition, no qres)
  if (t < R_){
    float qdot = 0.f, mdot = 0.f;
    const float* rrow = rcb + t*D_;
    const float* mrow = MT_f32 + t*C_;
    #pragma unroll 8
    for (int k = 0; k < D_; k += 4){
      float4 wv = *(const float4*)(rrow + k);
      qdot += qp[k]*wv.x + qp[k+1]*wv.y + qp[k+2]*wv.z + qp[k+3]*wv.w;
      float4 mv = *(const float4*)(mrow + k);
      mdot += cwl[k]*mv.x + cwl[k+1]*mv.y + cwl[k+2]*mv.z + cwl[k+3]*mv.w;
    }
    float Lr = (qdot - mdot) * INV16;
    float mr = wred_max(Lr);
    float er = __expf(Lr - mr);
    float sr = wred_sum(er);
    rcw_ws[n*R_ + t] = er / sr;
  }
}

// ---------------- K2: fused MFMA pass, wave-local softmax ----------------------
// block = (n, 64-s tile); 4 waves; wave w owns s-stripe [s0 + w*16, +16).
__global__ __launch_bounds__(256, 2) void k2(const float* __restrict__ Kt,
    const float* __restrict__ Vt, const ushortT* __restrict__ A1cat,
    const ushortT* __restrict__ MT_bf, const float* __restrict__ cw_ws,
    const float* __restrict__ rcw_ws, const float* __restrict__ rlogit,
    float* __restrict__ sum_ws, float* __restrict__ out_ew)
{
  __shared__ __align__(16) ushortT Ktile[64*256];   // 32 KB (sred overlay at end)
  __shared__ __align__(16) ushortT Wtile[64*256];   // 32 KB
  __shared__ float cwl[C_], rcwl[R_];

  int bx  = blockIdx.x;
  int n   = bx >> 2;
  int s0  = (bx & 3) * 64;
  int tid = threadIdx.x;
  int lane = tid & 63, w = tid >> 6;
  int l15 = lane & 15, l4 = lane >> 4;
  int srow = w*16 + l15;                 // this lane's s (local to tile)
  float gate  = 1.f / (1.f + __expf(-rlogit[0]));
  float inv1g = 1.f / (1.f + gate);

  const float* Kn = Kt + (size_t)n * S_ * D_ + (size_t)s0 * D_;
  const float* Vn = Vt + (size_t)n * S_ * D_ + (size_t)s0 * D_;

  // ---- stage: K tile (64x256) -> bf16 LDS (swizzled); cw/rcw -> LDS ----
  if (tid < C_) cwl[tid]  = cw_ws[n*C_ + tid];
  if (tid < R_) rcwl[tid] = rcw_ws[n*R_ + tid];
  #pragma unroll
  for (int j = 0; j < 8; j++){
    int ch = tid + j*256;                // 2048 chunks of 8 elems
    int row = ch >> 5, blk = ch & 31;
    const float* src = Kn + row*D_ + blk*8;
    float4 a = *(const float4*)src;
    float4 b = *(const float4*)(src + 4);
    uint4 wv = {packbf(a.x,a.y), packbf(a.z,a.w), packbf(b.x,b.y), packbf(b.z,b.w)};
    *(uint4*)((char*)Ktile + swz(row, blk*16)) = wv;
  }
  __syncthreads();                       // barrier 1

  // ---- GEMM1': [cb;rcb] (320 rows) x K-stripe -> acc[20] ----
  bf8 bK[8];
  #pragma unroll
  for (int k = 0; k < 8; k++)
    bK[k] = *(const bf8*)((const char*)Ktile + swz(srow, k*64 + l4*16));
  f4 acc[20];
  #pragma unroll
  for (int i = 0; i < 20; i++) acc[i] = (f4)0.f;
  const ushortT* Abase = A1cat + (size_t)l15*D_ + l4*8;
  #pragma unroll
  for (int rt = 0; rt < 20; rt++){
    const ushortT* ap = Abase + (size_t)rt*16*D_;
    #pragma unroll
    for (int k = 0; k < 8; k++){
      bf8 a = *(const bf8*)(ap + k*32);
      acc[rt] = __builtin_amdgcn_mfma_f32_16x16x32_bf16(a, bK[k], acc[rt], 0, 0, 0);
    }
  }

  // ---- softmax over c: fully wave-local (lane owns col s=srow) ----
  float se = 0.f, sb = 0.f;
  #pragma unroll
  for (int rt = 0; rt < 16; rt++)
    #pragma unroll
    for (int rg = 0; rg < 4; rg++){
      float e = __expf(acc[rt][rg] * INV16);
      acc[rt][rg] = e;
      se += e;
      sb += e * cwl[rt*16 + l4*4 + rg];
    }
  se += __shfl_xor(se, 16); se += __shfl_xor(se, 32);
  sb += __shfl_xor(sb, 16); sb += __shfl_xor(sb, 32);
  float rcp = 1.f / se;
  float bw  = sb * rcp;

  // ---- write W (bf16, swizzled): row s=srow, cols c ----
  #pragma unroll
  for (int rt = 0; rt < 16; rt++){
    uint2 u;
    u.x = packbf(acc[rt][0]*rcp, acc[rt][1]*rcp);
    u.y = packbf(acc[rt][2]*rcp, acc[rt][3]*rcp);
    *(uint2*)((char*)Wtile + swz(srow, rt*32 + l4*8)) = u;
  }
  __syncthreads();                       // barrier 2

  // ---- WM: MT (64 rows) x W-stripe -> wm[4]; L3 = acc[16..19] - wm ----
  bf8 bW[8];
  #pragma unroll
  for (int k = 0; k < 8; k++)
    bW[k] = *(const bf8*)((const char*)Wtile + swz(srow, k*64 + l4*16));
  f4 wm[4];
  #pragma unroll
  for (int i = 0; i < 4; i++) wm[i] = (f4)0.f;
  const ushortT* Mbase = MT_bf + (size_t)l15*C_ + l4*8;
  #pragma unroll
  for (int rt = 0; rt < 4; rt++){
    const ushortT* mp = Mbase + (size_t)rt*16*C_;
    #pragma unroll
    for (int k = 0; k < 8; k++){
      bf8 a = *(const bf8*)(mp + k*32);
      wm[rt] = __builtin_amdgcn_mfma_f32_16x16x32_bf16(a, bW[k], wm[rt], 0, 0, 0);
    }
  }

  // ---- softmax over r: wave-local ----
  float se3 = 0.f, sr3 = 0.f;
  #pragma unroll
  for (int rt = 0; rt < 4; rt++)
    #pragma unroll
    for (int rg = 0; rg < 4; rg++){
      float e = __expf((acc[16+rt][rg] - wm[rt][rg]) * INV16);
      se3 += e;
      sr3 += e * rcwl[rt*16 + l4*4 + rg];
    }
  se3 += __shfl_xor(se3, 16); se3 += __shfl_xor(se3, 32);
  sr3 += __shfl_xor(sr3, 16); sr3 += __shfl_xor(sr3, 32);
  float comb = bw + gate * (sr3 / se3);
  if (l4 == 0) out_ew[n*S_ + s0 + srow] = comb * inv1g;

  // ---- summary: wave-local, comb broadcast via shfl; no barrier ----
  float4 sacc = {0.f, 0.f, 0.f, 0.f};
  {
    const float* vp = Vn + (size_t)(w*16)*D_ + lane*4;
    #pragma unroll
    for (int j = 0; j < 16; j++){
      float cj = __shfl(comb, j);
      float4 v = *(const float4*)(vp + (size_t)j*D_);
      sacc.x = fmaf(cj, v.x, sacc.x); sacc.y = fmaf(cj, v.y, sacc.y);
      sacc.z = fmaf(cj, v.z, sacc.z); sacc.w = fmaf(cj, v.w, sacc.w);
    }
  }
  // cross-wave reduce (Ktile overlay) + atomic into sum_ws
  {
    float4* sred = (float4*)Ktile;       // [4][64] float4
    sred[w*64 + lane] = sacc;
  }
  __syncthreads();                       // barrier 3
  if (tid < 64){
    float4 a0 = ((float4*)Ktile)[tid],       a1 = ((float4*)Ktile)[64 + tid];
    float4 a2 = ((float4*)Ktile)[128 + tid], a3 = ((float4*)Ktile)[192 + tid];
    float* dst = sum_ws + (size_t)n*D_ + tid*4;
    atomicAdd(dst + 0, a0.x + a1.x + a2.x + a3.x);
    atomicAdd(dst + 1, a0.y + a1.y + a2.y + a3.y);
    atomicAdd(dst + 2, a0.z + a1.z + a2.z + a3.z);
    atomicAdd(dst + 3, a0.w + a1.w + a2.w + a3.w);
  }
}

// ---------------- K3: readout GEMM (MFMA, bf16) --------------------------------
__global__ __launch_bounds__(256) void k3(const float* __restrict__ sum_ws,
    const ushortT* __restrict__ Wcr_bf, const float* __restrict__ bc,
    const float* __restrict__ br, float* __restrict__ out)
{
  __shared__ __align__(16) ushortT Stile[64*256];   // 32 KB swizzled bf16 summary tile
  int bx = blockIdx.x;
  int ot = bx >> 4;           // 0..19 output tile (64 wide over [Wc;Wr;pad])
  int nt = bx & 15;           // 0..15 n tile (64 rows)
  int tid = threadIdx.x;
  int lane = tid & 63, wid = tid >> 6;
  int l15 = lane & 15, l4 = lane >> 4;

  const float* Sp = sum_ws + (size_t)nt*64*D_;
  #pragma unroll
  for (int j = 0; j < 8; j++){
    int ch = tid + j*256;
    int row = ch >> 5, blk = ch & 31;
    const float* src = Sp + row*D_ + blk*8;
    float4 a = *(const float4*)src;
    float4 b = *(const float4*)(src + 4);
    uint4 wv = {packbf(a.x,a.y), packbf(a.z,a.w), packbf(b.x,b.y), packbf(b.z,b.w)};
    *(uint4*)((char*)Stile + swz(row, blk*16)) = wv;
  }
  __syncthreads();

  int o0 = ot*64 + wid*16;
  const ushortT* Ap = Wcr_bf + (size_t)(o0 + l15)*D_ + l4*8;
  f4 acc[4];
  #pragma unroll
  for (int j = 0; j < 4; j++) acc[j] = (f4)0.f;
  #pragma unroll
  for (int k = 0; k < 8; k++){
    bf8 a = *(const bf8*)(Ap + k*32);
    #pragma unroll
    for (int nj = 0; nj < 4; nj++){
      bf8 b = *(const bf8*)((const char*)Stile + swz(nj*16 + l15, k*64 + l4*16));
      acc[nj] = __builtin_amdgcn_mfma_f32_16x16x32_bf16(a, b, acc[nj], 0, 0, 0);
    }
  }
  int obase = o0 + l4*4;
  if (obase < 1256){
    float4 bias;
    if (obase < CLS_) bias = *(const float4*)(bc + obase);
    else              bias = *(const float4*)(br + (obase - CLS_));
    #pragma unroll
    for (int nj = 0; nj < 4; nj++){
      int nn = nt*64 + nj*16 + l15;
      float4 v = {acc[nj][0]+bias.x, acc[nj][1]+bias.y, acc[nj][2]+bias.z, acc[nj][3]+bias.w};
      if (obase < CLS_) *(float4*)(out + (size_t)nn*CLS_ + obase) = v;
      else              *(float4*)(out + (size_t)N_*CLS_ + (size_t)nn*D_ + (obase - CLS_)) = v;
    }
  }
}

extern "C" void kernel_launch(void* const* d_in, const int* in_sizes, int n_in,
                              void* d_out, int out_size, void* d_ws, size_t ws_size,
                              hipStream_t stream)
{
  const float* q    = (const float*)d_in[0];
  const float* Kt   = (const float*)d_in[1];
  const float* Vt   = (const float*)d_in[2];
  const float* cb   = (const float*)d_in[3];
  const float* rcb  = (const float*)d_in[4];
  const float* Wq   = (const float*)d_in[5];
  const float* rlg  = (const float*)d_in[6];
  const float* Wc   = (const float*)d_in[7];
  const float* bc   = (const float*)d_in[8];
  const float* Wr   = (const float*)d_in[9];
  const float* br   = (const float*)d_in[10];
  float* out = (float*)d_out;
  float* ws  = (float*)d_ws;

  float* cw_ws  = ws;                          // N*C floats
  float* rcw_ws = ws + 262144;                 // N*R
  float* sum_ws = ws + 327680;                 // N*D
  float* MT_f32 = ws + 589824;                 // R*C
  ushortT* A1cat  = (ushortT*)(ws + 606208);   // 320*D bf16
  ushortT* MT_bf  = A1cat + (C_ + R_)*D_;      // R*C bf16
  ushortT* Wcr_bf = MT_bf + R_*C_;             // 1280*D bf16

  float* out_logits = out;
  float* out_ew     = out + (size_t)N_*CLS_ + (size_t)N_*D_;

  hipMemsetAsync(sum_ws, 0, (size_t)N_*D_*sizeof(float), stream);
  k0 <<<128,  256, 0, stream>>>(cb, rcb, Wc, Wr, A1cat, Wcr_bf);
  k0m<<<R_,   256, 0, stream>>>(cb, rcb, MT_f32, MT_bf);
  k1 <<<N_,   256, 0, stream>>>(q, cb, rcb, Wq, MT_f32, cw_ws, rcw_ws);
  k2 <<<N_*4, 256, 0, stream>>>(Kt, Vt, A1cat, MT_bf, cw_ws, rcw_ws, rlg,
                                sum_ws, out_ew);
  k3 <<<320,  256, 0, stream>>>(sum_ws, Wcr_bf, bc, br, out_logits);
}

// Round 6
// 296.776 us; speedup vs baseline: 1.6998x; 1.6998x over previous
//
#include <hip/hip_runtime.h>
#include <hip/hip_bf16.h>
#include <math.h>

#define N_   1024
#define S_   256
#define D_   256
#define C_   256
#define R_   64
#define CLS_ 1000
#define INV16 0.0625f

typedef unsigned short ushortT;
typedef unsigned int uint32;
typedef short bf8 __attribute__((ext_vector_type(8)));
typedef float f4 __attribute__((ext_vector_type(4)));

static __device__ __forceinline__ float bf2f(uint32 u){
  return __uint_as_float(u << 16);
}
static __device__ __forceinline__ ushortT f2bf(float f){
  uint32 x = __float_as_uint(f);
  uint32 r = x + 0x7FFFu + ((x >> 16) & 1u);
  return (ushortT)(r >> 16);
}
static __device__ __forceinline__ uint32 packbf(float a, float b){
  return ((uint32)f2bf(b) << 16) | (uint32)f2bf(a);
}
static __device__ __forceinline__ float wred_max(float v){
  for (int o = 32; o; o >>= 1) v = fmaxf(v, __shfl_xor(v, o));
  return v;
}
static __device__ __forceinline__ float wred_sum(float v){
  for (int o = 32; o; o >>= 1) v += __shfl_xor(v, o);
  return v;
}
// swizzled byte offset inside a [rows][256]-bf16 LDS tile (row stride 512B)
static __device__ __forceinline__ int swz(int row, int colbyte){
  return row*512 + ((colbyte & ~15) ^ ((row & 7) << 4)) + (colbyte & 15);
}
// fragment-ready packed index for a [rows x 256] matrix, 16-row frags, K-step 32
// (row, col) -> ushort index, nfrag = rows/16
static __device__ __forceinline__ int pkidx(int row, int col, int nfrag){
  int ks = col >> 5, hi = (col >> 3) & 3, e = col & 7;
  int frag = row >> 4, l15p = row & 15;
  return ((ks*nfrag + frag)*64 + hi*16 + l15p)*8 + e;
}

// ---------------- K0: bf16 weight prep (frag-packed A1cat, Wcr) ---------------
__global__ __launch_bounds__(256) void k0(const float* __restrict__ cb,
    const float* __restrict__ rcb, const float* __restrict__ Wc,
    const float* __restrict__ Wr, ushortT* __restrict__ a1pk,
    ushortT* __restrict__ Wcr_bf)
{
  int t = blockIdx.x*256 + threadIdx.x;
  int stride = gridDim.x*256;
  for (int e = t; e < (C_ + R_)*D_; e += stride){
    int row = e >> 8, col = e & 255;
    float v = (row < C_) ? cb[e] : rcb[e - C_*D_];
    a1pk[pkidx(row, col, 20)] = f2bf(v);
  }
  for (int e = t; e < CLS_*D_; e += stride) Wcr_bf[e] = f2bf(Wc[e]);
  for (int e = t; e < D_*D_; e += stride)  Wcr_bf[CLS_*D_ + e] = f2bf(Wr[e]);
  for (int e = t; e < 24*D_; e += stride)  Wcr_bf[1256*D_ + e] = 0;
}

// ---------------- K0m: M = cb @ rcb^T -> MT_f32 [r][c] + frag-packed bf16 -----
__global__ __launch_bounds__(256) void k0m(const float* __restrict__ cb,
    const float* __restrict__ rcb, float* __restrict__ MT_f32,
    ushortT* __restrict__ mtpk)
{
  __shared__ float rl[D_];
  int r = blockIdx.x;        // 0..63
  int t = threadIdx.x;       // c = 0..255
  rl[t] = rcb[r*D_ + t];
  __syncthreads();
  float acc = 0.f;
  const float* crow = cb + t*D_;
  #pragma unroll 8
  for (int k = 0; k < D_; k += 4){
    float4 w = *(const float4*)(crow + k);
    acc += w.x*rl[k] + w.y*rl[k+1] + w.z*rl[k+2] + w.w*rl[k+3];
  }
  MT_f32[r*C_ + t] = acc;
  mtpk[pkidx(r, t, 4)] = f2bf(acc);
}

// ---------------- K1: per-query pass ------------------------------------------
__global__ __launch_bounds__(256) void k1(const float* __restrict__ q,
    const float* __restrict__ cb, const float* __restrict__ rcb,
    const float* __restrict__ Wq, const float* __restrict__ MT_f32,
    float* __restrict__ cw_ws, float* __restrict__ rcw_ws)
{
  __shared__ float qv[D_], qp[D_], red[8], redB[8], cwl[C_];
  int n = blockIdx.x, t = threadIdx.x;
  qv[t] = q[n*D_ + t];
  __syncthreads();
  {
    float acc = 0.f;
    const float* wrow = Wq + t*D_;
    #pragma unroll 8
    for (int k = 0; k < D_; k += 4){
      float4 w = *(const float4*)(wrow + k);
      acc += qv[k]*w.x + qv[k+1]*w.y + qv[k+2]*w.z + qv[k+3]*w.w;
    }
    qp[t] = acc;
  }
  __syncthreads();
  float L = 0.f;
  {
    const float* crow = cb + t*D_;
    #pragma unroll 8
    for (int k = 0; k < D_; k += 4){
      float4 w = *(const float4*)(crow + k);
      L += qp[k]*w.x + qp[k+1]*w.y + qp[k+2]*w.z + qp[k+3]*w.w;
    }
    L *= INV16;
  }
  float m = wred_max(L);
  if ((t & 63) == 0) red[t >> 6] = m;
  __syncthreads();
  m = fmaxf(fmaxf(red[0], red[1]), fmaxf(red[2], red[3]));
  float e = __expf(L - m);
  float s = wred_sum(e);
  if ((t & 63) == 0) redB[t >> 6] = s;
  __syncthreads();
  s = redB[0] + redB[1] + redB[2] + redB[3];
  float w = e / s;
  cwl[t] = w;
  cw_ws[n*C_ + t] = w;
  __syncthreads();
  if (t < R_){
    float qdot = 0.f, mdot = 0.f;
    const float* rrow = rcb + t*D_;
    const float* mrow = MT_f32 + t*C_;
    #pragma unroll 8
    for (int k = 0; k < D_; k += 4){
      float4 wv = *(const float4*)(rrow + k);
      qdot += qp[k]*wv.x + qp[k+1]*wv.y + qp[k+2]*wv.z + qp[k+3]*wv.w;
      float4 mv = *(const float4*)(mrow + k);
      mdot += cwl[k]*mv.x + cwl[k+1]*mv.y + cwl[k+2]*mv.z + cwl[k+3]*mv.w;
    }
    float Lr = (qdot - mdot) * INV16;
    float mr = wred_max(Lr);
    float er = __expf(Lr - mr);
    float sr = wred_sum(er);
    rcw_ws[n*R_ + t] = er / sr;
  }
}

// ---------------- K2: fused MFMA pass, operand-resident, 6 barriers -----------
// block = (n, 64-s tile); 4 waves; wave w owns cr-frags {w,4+w,8+w,12+w,16+w}.
__global__ __launch_bounds__(256, 2) void k2(const float* __restrict__ Kt,
    const float* __restrict__ Vt, const ushortT* __restrict__ a1pk,
    const ushortT* __restrict__ mtpk, const float* __restrict__ cw_ws,
    const float* __restrict__ rcw_ws, const float* __restrict__ rlogit,
    float* __restrict__ sum_ws, float* __restrict__ out_ew)
{
  __shared__ __align__(16) ushortT KW[64*256];    // 32 KB: Ktile, then Wtile (swz)
  __shared__ __align__(16) ushortT MTl[16384];    // 32 KB: MT frag-linear
  __shared__ float redS[4][64], redW[4][64];
  __shared__ float bwl[64], combl[64];
  __shared__ float cwl[C_], rcwl[R_];

  int bx  = blockIdx.x;
  int n   = bx >> 2;
  int s0  = (bx & 3) * 64;
  int tid = threadIdx.x;
  int lane = tid & 63, w = tid >> 6;
  int l15 = lane & 15, l4 = lane >> 4;
  float gate  = 1.f / (1.f + __expf(-rlogit[0]));
  float inv1g = 1.f / (1.f + gate);

  const float* Kn = Kt + (size_t)n * S_ * D_ + (size_t)s0 * D_;
  const float* Vn = Vt + (size_t)n * S_ * D_ + (size_t)s0 * D_;

  if (tid < C_) cwl[tid]  = cw_ws[n*C_ + tid];
  if (tid < R_) rcwl[tid] = rcw_ws[n*R_ + tid];

  // ---- stage K tile (64x256) fp32 -> bf16 swz LDS ----
  #pragma unroll
  for (int j = 0; j < 8; j++){
    int ch = tid + j*256;
    int row = ch >> 5, blk = ch & 31;
    const float* src = Kn + row*D_ + blk*8;
    float4 a = *(const float4*)src;
    float4 b = *(const float4*)(src + 4);
    uint4 wv = {packbf(a.x,a.y), packbf(a.z,a.w), packbf(b.x,b.y), packbf(b.z,b.w)};
    *(uint4*)((char*)KW + swz(row, blk*16)) = wv;
  }
  __syncthreads();                                   // B1

  float cw_r[16];
  #pragma unroll
  for (int f = 0; f < 4; f++)
    #pragma unroll
    for (int rg = 0; rg < 4; rg++)
      cw_r[f*4+rg] = cwl[(w + 4*f)*16 + l4*4 + rg];
  float rcw_r[4];
  #pragma unroll
  for (int rg = 0; rg < 4; rg++) rcw_r[rg] = rcwl[w*16 + l4*4 + rg];

  // ---- GEMM1': [cb;rcb](320) x Ktile^T -> acc[5][4]; B-frags reg-prefetched --
  const ushortT* a1w = a1pk + (size_t)(w*64 + lane)*8;   // frag stride 512 ushorts
  bf8 bnx[5];
  #pragma unroll
  for (int f = 0; f < 5; f++)
    bnx[f] = *(const bf8*)(a1w + (size_t)(4*f)*512);
  f4 acc[5][4];
  #pragma unroll
  for (int f = 0; f < 5; f++)
    #pragma unroll
    for (int sj = 0; sj < 4; sj++) acc[f][sj] = (f4)0.f;
  #pragma unroll
  for (int ks = 0; ks < 8; ks++){
    bf8 bc[5];
    #pragma unroll
    for (int f = 0; f < 5; f++) bc[f] = bnx[f];
    if (ks < 7){
      #pragma unroll
      for (int f = 0; f < 5; f++)
        bnx[f] = *(const bf8*)(a1w + (size_t)((ks+1)*20 + 4*f)*512);
    }
    bf8 kf[4];
    #pragma unroll
    for (int sj = 0; sj < 4; sj++)
      kf[sj] = *(const bf8*)((const char*)KW + swz(sj*16 + l15, ks*64 + l4*16));
    #pragma unroll
    for (int f = 0; f < 5; f++)
      #pragma unroll
      for (int sj = 0; sj < 4; sj++)
        acc[f][sj] = __builtin_amdgcn_mfma_f32_16x16x32_bf16(bc[f], kf[sj], acc[f][sj], 0, 0, 0);
  }

  // ---- issue MT global->reg (written to LDS after B2) ----
  uint4 mtv[8];
  #pragma unroll
  for (int j = 0; j < 8; j++)
    mtv[j] = *(const uint4*)(mtpk + (size_t)(tid + j*256)*8);

  // ---- softmax over c: exp in-place, wave-local partial, LDS combine --------
  float se[4] = {0,0,0,0}, sb[4] = {0,0,0,0};
  #pragma unroll
  for (int f = 0; f < 4; f++)
    #pragma unroll
    for (int sj = 0; sj < 4; sj++)
      #pragma unroll
      for (int rg = 0; rg < 4; rg++){
        float e = __expf(acc[f][sj][rg] * INV16);
        acc[f][sj][rg] = e;
        se[sj] += e;
        sb[sj] += e * cw_r[f*4+rg];
      }
  #pragma unroll
  for (int sj = 0; sj < 4; sj++){
    se[sj] += __shfl_xor(se[sj], 16); se[sj] += __shfl_xor(se[sj], 32);
    sb[sj] += __shfl_xor(sb[sj], 16); sb[sj] += __shfl_xor(sb[sj], 32);
  }
  if (l4 == 0){
    #pragma unroll
    for (int sj = 0; sj < 4; sj++){
      redS[w][sj*16 + l15] = se[sj];
      redW[w][sj*16 + l15] = sb[sj];
    }
  }
  __syncthreads();                                   // B2 (GEMM1 K-reads done)
  float rcp[4];
  #pragma unroll
  for (int sj = 0; sj < 4; sj++){
    int s_ = sj*16 + l15;
    float sS = redS[0][s_] + redS[1][s_] + redS[2][s_] + redS[3][s_];
    float sW = redW[0][s_] + redW[1][s_] + redW[2][s_] + redW[3][s_];
    rcp[sj] = 1.f / sS;
    if (w == 0 && l4 == 0) bwl[s_] = sW / sS;
  }
  // ---- W (bf16, swz) into KW (Ktile dead); MT regs -> LDS ----
  #pragma unroll
  for (int f = 0; f < 4; f++){
    int cbyte = ((w + 4*f)*16 + l4*4) * 2;
    #pragma unroll
    for (int sj = 0; sj < 4; sj++){
      int s_ = sj*16 + l15;
      float r = rcp[sj];
      *(uint32*)((char*)KW + swz(s_, cbyte))     = packbf(acc[f][sj][0]*r, acc[f][sj][1]*r);
      *(uint32*)((char*)KW + swz(s_, cbyte + 4)) = packbf(acc[f][sj][2]*r, acc[f][sj][3]*r);
    }
  }
  #pragma unroll
  for (int j = 0; j < 8; j++)
    *(uint4*)(&MTl[(size_t)(tid + j*256)*8]) = mtv[j];
  __syncthreads();                                   // B3

  // ---- WM: MT(64) x W^T -> wmacc[4] (wave owns r-frag w) --------------------
  f4 wmacc[4];
  #pragma unroll
  for (int sj = 0; sj < 4; sj++) wmacc[sj] = (f4)0.f;
  #pragma unroll
  for (int ks = 0; ks < 8; ks++){
    bf8 a = *(const bf8*)(&MTl[(size_t)((ks*4 + w)*64 + lane)*8]);
    #pragma unroll
    for (int sj = 0; sj < 4; sj++){
      bf8 b = *(const bf8*)((const char*)KW + swz(sj*16 + l15, ks*64 + l4*16));
      wmacc[sj] = __builtin_amdgcn_mfma_f32_16x16x32_bf16(a, b, wmacc[sj], 0, 0, 0);
    }
  }

  // ---- softmax over r: l3 = (acc[4]-wm)/16, wave-local + LDS combine --------
  float se3[4] = {0,0,0,0}, sc3[4] = {0,0,0,0};
  #pragma unroll
  for (int sj = 0; sj < 4; sj++)
    #pragma unroll
    for (int rg = 0; rg < 4; rg++){
      float e = __expf((acc[4][sj][rg] - wmacc[sj][rg]) * INV16);
      se3[sj] += e;
      sc3[sj] += e * rcw_r[rg];
    }
  #pragma unroll
  for (int sj = 0; sj < 4; sj++){
    se3[sj] += __shfl_xor(se3[sj], 16); se3[sj] += __shfl_xor(se3[sj], 32);
    sc3[sj] += __shfl_xor(sc3[sj], 16); sc3[sj] += __shfl_xor(sc3[sj], 32);
  }
  if (l4 == 0){
    #pragma unroll
    for (int sj = 0; sj < 4; sj++){
      redS[w][sj*16 + l15] = se3[sj];
      redW[w][sj*16 + l15] = sc3[sj];
    }
  }
  __syncthreads();                                   // B4
  if (w == 0 && l4 == 0){
    #pragma unroll
    for (int sj = 0; sj < 4; sj++){
      int s_ = sj*16 + l15;
      float sS = redS[0][s_] + redS[1][s_] + redS[2][s_] + redS[3][s_];
      float sW = redW[0][s_] + redW[1][s_] + redW[2][s_] + redW[3][s_];
      float comb = bwl[s_] + gate * (sW / sS);
      combl[s_] = comb;
      out_ew[n*S_ + s0 + s_] = comb * inv1g;
    }
  }
  __syncthreads();                                   // B5

  // ---- summary: wave w handles s-rows [w*16, +16), lane covers 4 d ----------
  {
    float4 sacc = {0.f, 0.f, 0.f, 0.f};
    const float* vp = Vn + (size_t)(w*16)*D_ + lane*4;
    #pragma unroll
    for (int j = 0; j < 16; j++){
      float cj = combl[w*16 + j];
      float4 v = *(const float4*)(vp + (size_t)j*D_);
      sacc.x = fmaf(cj, v.x, sacc.x); sacc.y = fmaf(cj, v.y, sacc.y);
      sacc.z = fmaf(cj, v.z, sacc.z); sacc.w = fmaf(cj, v.w, sacc.w);
    }
    float4* sred = (float4*)KW;                      // overlay [4][64] float4
    sred[w*64 + lane] = sacc;
  }
  __syncthreads();                                   // B6
  if (tid < 64){
    float4 a0 = ((float4*)KW)[tid],       a1 = ((float4*)KW)[64 + tid];
    float4 a2 = ((float4*)KW)[128 + tid], a3 = ((float4*)KW)[192 + tid];
    float* dst = sum_ws + (size_t)n*D_ + tid*4;
    atomicAdd(dst + 0, a0.x + a1.x + a2.x + a3.x);
    atomicAdd(dst + 1, a0.y + a1.y + a2.y + a3.y);
    atomicAdd(dst + 2, a0.z + a1.z + a2.z + a3.z);
    atomicAdd(dst + 3, a0.w + a1.w + a2.w + a3.w);
  }
}

// ---------------- K3: readout GEMM (MFMA, bf16) --------------------------------
__global__ __launch_bounds__(256) void k3(const float* __restrict__ sum_ws,
    const ushortT* __restrict__ Wcr_bf, const float* __restrict__ bc,
    const float* __restrict__ br, float* __restrict__ out)
{
  __shared__ __align__(16) ushortT Stile[64*256];   // 32 KB swizzled bf16 summary tile
  int bx = blockIdx.x;
  int ot = bx >> 4;           // 0..19 output tile (64 wide over [Wc;Wr;pad])
  int nt = bx & 15;           // 0..15 n tile (64 rows)
  int tid = threadIdx.x;
  int lane = tid & 63, wid = tid >> 6;
  int l15 = lane & 15, l4 = lane >> 4;

  const float* Sp = sum_ws + (size_t)nt*64*D_;
  #pragma unroll
  for (int j = 0; j < 8; j++){
    int ch = tid + j*256;
    int row = ch >> 5, blk = ch & 31;
    const float* src = Sp + row*D_ + blk*8;
    float4 a = *(const float4*)src;
    float4 b = *(const float4*)(src + 4);
    uint4 wv = {packbf(a.x,a.y), packbf(a.z,a.w), packbf(b.x,b.y), packbf(b.z,b.w)};
    *(uint4*)((char*)Stile + swz(row, blk*16)) = wv;
  }
  __syncthreads();

  int o0 = ot*64 + wid*16;
  const ushortT* Ap = Wcr_bf + (size_t)(o0 + l15)*D_ + l4*8;
  f4 acc[4];
  #pragma unroll
  for (int j = 0; j < 4; j++) acc[j] = (f4)0.f;
  #pragma unroll
  for (int k = 0; k < 8; k++){
    bf8 a = *(const bf8*)(Ap + k*32);
    #pragma unroll
    for (int nj = 0; nj < 4; nj++){
      bf8 b = *(const bf8*)((const char*)Stile + swz(nj*16 + l15, k*64 + l4*16));
      acc[nj] = __builtin_amdgcn_mfma_f32_16x16x32_bf16(a, b, acc[nj], 0, 0, 0);
    }
  }
  int obase = o0 + l4*4;
  if (obase < 1256){
    float4 bias;
    if (obase < CLS_) bias = *(const float4*)(bc + obase);
    else              bias = *(const float4*)(br + (obase - CLS_));
    #pragma unroll
    for (int nj = 0; nj < 4; nj++){
      int nn = nt*64 + nj*16 + l15;
      float4 v = {acc[nj][0]+bias.x, acc[nj][1]+bias.y, acc[nj][2]+bias.z, acc[nj][3]+bias.w};
      if (obase < CLS_) *(float4*)(out + (size_t)nn*CLS_ + obase) = v;
      else              *(float4*)(out + (size_t)N_*CLS_ + (size_t)nn*D_ + (obase - CLS_)) = v;
    }
  }
}

extern "C" void kernel_launch(void* const* d_in, const int* in_sizes, int n_in,
                              void* d_out, int out_size, void* d_ws, size_t ws_size,
                              hipStream_t stream)
{
  const float* q    = (const float*)d_in[0];
  const float* Kt   = (const float*)d_in[1];
  const float* Vt   = (const float*)d_in[2];
  const float* cb   = (const float*)d_in[3];
  const float* rcb  = (const float*)d_in[4];
  const float* Wq   = (const float*)d_in[5];
  const float* rlg  = (const float*)d_in[6];
  const float* Wc   = (const float*)d_in[7];
  const float* bc   = (const float*)d_in[8];
  const float* Wr   = (const float*)d_in[9];
  const float* br   = (const float*)d_in[10];
  float* out = (float*)d_out;
  float* ws  = (float*)d_ws;

  float* cw_ws  = ws;                          // N*C floats
  float* rcw_ws = ws + 262144;                 // N*R
  float* sum_ws = ws + 327680;                 // N*D
  float* MT_f32 = ws + 589824;                 // R*C
  ushortT* a1pk   = (ushortT*)(ws + 606208);   // 320*D frag-packed
  ushortT* mtpk   = a1pk + (C_ + R_)*D_;       // R*C frag-packed
  ushortT* Wcr_bf = mtpk + R_*C_;              // 1280*D (Wc ; Wr ; zero pad)

  float* out_logits = out;
  float* out_ew     = out + (size_t)N_*CLS_ + (size_t)N_*D_;

  hipMemsetAsync(sum_ws, 0, (size_t)N_*D_*sizeof(float), stream);
  k0 <<<128,  256, 0, stream>>>(cb, rcb, Wc, Wr, a1pk, Wcr_bf);
  k0m<<<R_,   256, 0, stream>>>(cb, rcb, MT_f32, mtpk);
  k1 <<<N_,   256, 0, stream>>>(q, cb, rcb, Wq, MT_f32, cw_ws, rcw_ws);
  k2 <<<N_*4, 256, 0, stream>>>(Kt, Vt, a1pk, mtpk, cw_ws, rcw_ws, rlg,
                                sum_ws, out_ew);
  k3 <<<320,  256, 0, stream>>>(sum_ws, Wcr_bf, bc, br, out_logits);
}

// Round 7
// 257.694 us; speedup vs baseline: 1.9576x; 1.1517x over previous
//
#include <hip/hip_runtime.h>
#include <hip/hip_bf16.h>
#include <math.h>

#define N_   1024
#define S_   256
#define D_   256
#define C_   256
#define R_   64
#define CLS_ 1000
#define INV16 0.0625f

typedef unsigned short ushortT;
typedef unsigned int uint32;
typedef short bf8 __attribute__((ext_vector_type(8)));
typedef float f4 __attribute__((ext_vector_type(4)));

static __device__ __forceinline__ float bf2f(uint32 u){
  return __uint_as_float(u << 16);
}
static __device__ __forceinline__ ushortT f2bf(float f){
  uint32 x = __float_as_uint(f);
  uint32 r = x + 0x7FFFu + ((x >> 16) & 1u);
  return (ushortT)(r >> 16);
}
static __device__ __forceinline__ uint32 packbf(float a, float b){
  return ((uint32)f2bf(b) << 16) | (uint32)f2bf(a);
}
static __device__ __forceinline__ float wred_max(float v){
  for (int o = 32; o; o >>= 1) v = fmaxf(v, __shfl_xor(v, o));
  return v;
}
static __device__ __forceinline__ float wred_sum(float v){
  for (int o = 32; o; o >>= 1) v += __shfl_xor(v, o);
  return v;
}
// swizzled byte offset inside a [rows][256]-bf16 LDS tile (row stride 512B)
static __device__ __forceinline__ int swz(int row, int colbyte){
  return row*512 + ((colbyte & ~15) ^ ((row & 7) << 4)) + (colbyte & 15);
}
// fragment-ready packed index for a [rows x 256] matrix, 16-row frags, K-step 32
static __device__ __forceinline__ int pkidx(int row, int col, int nfrag){
  int ks = col >> 5, hi = (col >> 3) & 3, e = col & 7;
  int frag = row >> 4, l15p = row & 15;
  return ((ks*nfrag + frag)*64 + hi*16 + l15p)*8 + e;
}

// ---------------- K0: bf16 weight prep (frag-packed A1cat, Wcr) ---------------
__global__ __launch_bounds__(256) void k0(const float* __restrict__ cb,
    const float* __restrict__ rcb, const float* __restrict__ Wc,
    const float* __restrict__ Wr, ushortT* __restrict__ a1pk,
    ushortT* __restrict__ Wcr_bf)
{
  int t = blockIdx.x*256 + threadIdx.x;
  int stride = gridDim.x*256;
  for (int e = t; e < (C_ + R_)*D_; e += stride){
    int row = e >> 8, col = e & 255;
    float v = (row < C_) ? cb[e] : rcb[e - C_*D_];
    a1pk[pkidx(row, col, 20)] = f2bf(v);
  }
  for (int e = t; e < CLS_*D_; e += stride) Wcr_bf[e] = f2bf(Wc[e]);
  for (int e = t; e < D_*D_; e += stride)  Wcr_bf[CLS_*D_ + e] = f2bf(Wr[e]);
  for (int e = t; e < 24*D_; e += stride)  Wcr_bf[1256*D_ + e] = 0;
}

// ---------------- K0m: M = cb @ rcb^T -> MT_f32 [r][c] + frag-packed bf16 -----
__global__ __launch_bounds__(256) void k0m(const float* __restrict__ cb,
    const float* __restrict__ rcb, float* __restrict__ MT_f32,
    ushortT* __restrict__ mtpk)
{
  __shared__ float rl[D_];
  int r = blockIdx.x;        // 0..63
  int t = threadIdx.x;       // c = 0..255
  rl[t] = rcb[r*D_ + t];
  __syncthreads();
  float acc = 0.f;
  const float* crow = cb + t*D_;
  #pragma unroll 8
  for (int k = 0; k < D_; k += 4){
    float4 w = *(const float4*)(crow + k);
    acc += w.x*rl[k] + w.y*rl[k+1] + w.z*rl[k+2] + w.w*rl[k+3];
  }
  MT_f32[r*C_ + t] = acc;
  mtpk[pkidx(r, t, 4)] = f2bf(acc);
}

// ---------------- K1: per-query pass ------------------------------------------
__global__ __launch_bounds__(256) void k1(const float* __restrict__ q,
    const float* __restrict__ cb, const float* __restrict__ rcb,
    const float* __restrict__ Wq, const float* __restrict__ MT_f32,
    float* __restrict__ cw_ws, float* __restrict__ rcw_ws)
{
  __shared__ float qv[D_], qp[D_], red[8], redB[8], cwl[C_];
  int n = blockIdx.x, t = threadIdx.x;
  qv[t] = q[n*D_ + t];
  __syncthreads();
  {
    float acc = 0.f;
    const float* wrow = Wq + t*D_;
    #pragma unroll 8
    for (int k = 0; k < D_; k += 4){
      float4 w = *(const float4*)(wrow + k);
      acc += qv[k]*w.x + qv[k+1]*w.y + qv[k+2]*w.z + qv[k+3]*w.w;
    }
    qp[t] = acc;
  }
  __syncthreads();
  float L = 0.f;
  {
    const float* crow = cb + t*D_;
    #pragma unroll 8
    for (int k = 0; k < D_; k += 4){
      float4 w = *(const float4*)(crow + k);
      L += qp[k]*w.x + qp[k+1]*w.y + qp[k+2]*w.z + qp[k+3]*w.w;
    }
    L *= INV16;
  }
  float m = wred_max(L);
  if ((t & 63) == 0) red[t >> 6] = m;
  __syncthreads();
  m = fmaxf(fmaxf(red[0], red[1]), fmaxf(red[2], red[3]));
  float e = __expf(L - m);
  float s = wred_sum(e);
  if ((t & 63) == 0) redB[t >> 6] = s;
  __syncthreads();
  s = redB[0] + redB[1] + redB[2] + redB[3];
  float w = e / s;
  cwl[t] = w;
  cw_ws[n*C_ + t] = w;
  __syncthreads();
  if (t < R_){
    float qdot = 0.f, mdot = 0.f;
    const float* rrow = rcb + t*D_;
    const float* mrow = MT_f32 + t*C_;
    #pragma unroll 8
    for (int k = 0; k < D_; k += 4){
      float4 wv = *(const float4*)(rrow + k);
      qdot += qp[k]*wv.x + qp[k+1]*wv.y + qp[k+2]*wv.z + qp[k+3]*wv.w;
      float4 mv = *(const float4*)(mrow + k);
      mdot += cwl[k]*mv.x + cwl[k+1]*mv.y + cwl[k+2]*mv.z + cwl[k+3]*mv.w;
    }
    float Lr = (qdot - mdot) * INV16;
    float mr = wred_max(Lr);
    float er = __expf(Lr - mr);
    float sr = wred_sum(er);
    rcw_ws[n*R_ + t] = er / sr;
  }
}

// ---------------- K2: fused MFMA pass, operand-resident, 5 barriers -----------
// block = (n, 64-s tile); 4 waves; wave w owns cr-frags {w,4+w,8+w,12+w,16+w}
// and s-stripe [w*16, +16) for comb/summary.
__global__ __launch_bounds__(256, 2) void k2(const float* __restrict__ Kt,
    const float* __restrict__ Vt, const ushortT* __restrict__ a1pk,
    const ushortT* __restrict__ mtpk, const float* __restrict__ cw_ws,
    const float* __restrict__ rcw_ws, const float* __restrict__ rlogit,
    float* __restrict__ sum_ws, float* __restrict__ out_ew)
{
  __shared__ __align__(16) ushortT KW[64*256];    // 32 KB: Ktile, then Wtile (swz)
  __shared__ __align__(16) ushortT MTl[16384];    // 32 KB: MT frag-linear
  __shared__ float redS[4][64], redW[4][64];      // reused by both softmaxes
  __shared__ float cwl[C_], rcwl[R_];

  int bx  = blockIdx.x;
  int n   = bx >> 2;
  int s0  = (bx & 3) * 64;
  int tid = threadIdx.x;
  int lane = tid & 63, w = tid >> 6;
  int l15 = lane & 15, l4 = lane >> 4;
  int sabs = w*16 + l15;                // this wave's owned s-row (per l15)
  float gate  = 1.f / (1.f + __expf(-rlogit[0]));
  float inv1g = 1.f / (1.f + gate);

  const float* Kn = Kt + (size_t)n * S_ * D_ + (size_t)s0 * D_;
  const float* Vn = Vt + (size_t)n * S_ * D_ + (size_t)s0 * D_;

  if (tid < C_) cwl[tid]  = cw_ws[n*C_ + tid];
  if (tid < R_) rcwl[tid] = rcw_ws[n*R_ + tid];

  // ---- stage MT (L2-resident) -> LDS, then K tile (HBM) -> bf16 swz LDS ----
  #pragma unroll
  for (int j = 0; j < 8; j++)
    *(uint4*)(&MTl[(size_t)(tid + j*256)*8]) =
        *(const uint4*)(mtpk + (size_t)(tid + j*256)*8);
  #pragma unroll
  for (int j = 0; j < 8; j++){
    int ch = tid + j*256;
    int row = ch >> 5, blk = ch & 31;
    const float* src = Kn + row*D_ + blk*8;
    float4 a = *(const float4*)src;
    float4 b = *(const float4*)(src + 4);
    uint4 wv = {packbf(a.x,a.y), packbf(a.z,a.w), packbf(b.x,b.y), packbf(b.z,b.w)};
    *(uint4*)((char*)KW + swz(row, blk*16)) = wv;
  }
  __syncthreads();                                   // B1

  float cw_r[16];
  #pragma unroll
  for (int f = 0; f < 4; f++)
    #pragma unroll
    for (int rg = 0; rg < 4; rg++)
      cw_r[f*4+rg] = cwl[(w + 4*f)*16 + l4*4 + rg];
  float rcw_r[4];
  #pragma unroll
  for (int rg = 0; rg < 4; rg++) rcw_r[rg] = rcwl[w*16 + l4*4 + rg];

  // ---- GEMM1': [cb;rcb](320) x Ktile^T -> acc[5][4]; B-frags reg-prefetched --
  const ushortT* a1w = a1pk + (size_t)(w*64 + lane)*8;   // frag stride 512 ushorts
  bf8 bnx[5];
  #pragma unroll
  for (int f = 0; f < 5; f++)
    bnx[f] = *(const bf8*)(a1w + (size_t)(4*f)*512);
  f4 acc[5][4];
  #pragma unroll
  for (int f = 0; f < 5; f++)
    #pragma unroll
    for (int sj = 0; sj < 4; sj++) acc[f][sj] = (f4)0.f;
  #pragma unroll
  for (int ks = 0; ks < 8; ks++){
    bf8 bcur[5];
    #pragma unroll
    for (int f = 0; f < 5; f++) bcur[f] = bnx[f];
    if (ks < 7){
      #pragma unroll
      for (int f = 0; f < 5; f++)
        bnx[f] = *(const bf8*)(a1w + (size_t)((ks+1)*20 + 4*f)*512);
    }
    bf8 kf[4];
    #pragma unroll
    for (int sj = 0; sj < 4; sj++)
      kf[sj] = *(const bf8*)((const char*)KW + swz(sj*16 + l15, ks*64 + l4*16));
    #pragma unroll
    for (int f = 0; f < 5; f++)
      #pragma unroll
      for (int sj = 0; sj < 4; sj++)
        acc[f][sj] = __builtin_amdgcn_mfma_f32_16x16x32_bf16(bcur[f], kf[sj], acc[f][sj], 0, 0, 0);
  }

  // ---- softmax over c: exp in-place, wave-local partial, LDS combine --------
  float se[4] = {0,0,0,0}, sb[4] = {0,0,0,0};
  #pragma unroll
  for (int f = 0; f < 4; f++)
    #pragma unroll
    for (int sj = 0; sj < 4; sj++)
      #pragma unroll
      for (int rg = 0; rg < 4; rg++){
        float e = __expf(acc[f][sj][rg] * INV16);
        acc[f][sj][rg] = e;
        se[sj] += e;
        sb[sj] += e * cw_r[f*4+rg];
      }
  #pragma unroll
  for (int sj = 0; sj < 4; sj++){
    se[sj] += __shfl_xor(se[sj], 16); se[sj] += __shfl_xor(se[sj], 32);
    sb[sj] += __shfl_xor(sb[sj], 16); sb[sj] += __shfl_xor(sb[sj], 32);
  }
  if (l4 == 0){
    #pragma unroll
    for (int sj = 0; sj < 4; sj++){
      redS[w][sj*16 + l15] = se[sj];
      redW[w][sj*16 + l15] = sb[sj];
    }
  }
  __syncthreads();                                   // B2 (GEMM1 K-reads done)
  float rcp[4];
  #pragma unroll
  for (int sj = 0; sj < 4; sj++){
    int s_ = sj*16 + l15;
    rcp[sj] = 1.f / (redS[0][s_] + redS[1][s_] + redS[2][s_] + redS[3][s_]);
  }
  float bw_loc;     // base weight for this wave's owned s-row
  {
    float sS = redS[0][sabs] + redS[1][sabs] + redS[2][sabs] + redS[3][sabs];
    float sW = redW[0][sabs] + redW[1][sabs] + redW[2][sabs] + redW[3][sabs];
    bw_loc = sW / sS;
  }
  // ---- W (bf16, swz) into KW (Ktile dead) ----
  #pragma unroll
  for (int f = 0; f < 4; f++){
    int cbyte = ((w + 4*f)*16 + l4*4) * 2;
    #pragma unroll
    for (int sj = 0; sj < 4; sj++){
      int s_ = sj*16 + l15;
      float r = rcp[sj];
      *(uint32*)((char*)KW + swz(s_, cbyte))     = packbf(acc[f][sj][0]*r, acc[f][sj][1]*r);
      *(uint32*)((char*)KW + swz(s_, cbyte + 4)) = packbf(acc[f][sj][2]*r, acc[f][sj][3]*r);
    }
  }
  __syncthreads();                                   // B3

  // ---- WM: MT(64) x W^T -> wmacc[4] (wave owns r-frag w) --------------------
  f4 wmacc[4];
  #pragma unroll
  for (int sj = 0; sj < 4; sj++) wmacc[sj] = (f4)0.f;
  #pragma unroll
  for (int ks = 0; ks < 8; ks++){
    bf8 a = *(const bf8*)(&MTl[(size_t)((ks*4 + w)*64 + lane)*8]);
    #pragma unroll
    for (int sj = 0; sj < 4; sj++){
      bf8 b = *(const bf8*)((const char*)KW + swz(sj*16 + l15, ks*64 + l4*16));
      wmacc[sj] = __builtin_amdgcn_mfma_f32_16x16x32_bf16(a, b, wmacc[sj], 0, 0, 0);
    }
  }

  // ---- softmax over r: l3 = (acc[4]-wm)/16, wave-local + LDS combine --------
  float se3[4] = {0,0,0,0}, sc3[4] = {0,0,0,0};
  #pragma unroll
  for (int sj = 0; sj < 4; sj++)
    #pragma unroll
    for (int rg = 0; rg < 4; rg++){
      float e = __expf((acc[4][sj][rg] - wmacc[sj][rg]) * INV16);
      se3[sj] += e;
      sc3[sj] += e * rcw_r[rg];
    }
  #pragma unroll
  for (int sj = 0; sj < 4; sj++){
    se3[sj] += __shfl_xor(se3[sj], 16); se3[sj] += __shfl_xor(se3[sj], 32);
    sc3[sj] += __shfl_xor(sc3[sj], 16); sc3[sj] += __shfl_xor(sc3[sj], 32);
  }
  if (l4 == 0){
    #pragma unroll
    for (int sj = 0; sj < 4; sj++){
      redS[w][sj*16 + l15] = se3[sj];
      redW[w][sj*16 + l15] = sc3[sj];
    }
  }
  __syncthreads();                                   // B4
  float comb;
  {
    float sS = redS[0][sabs] + redS[1][sabs] + redS[2][sabs] + redS[3][sabs];
    float sW = redW[0][sabs] + redW[1][sabs] + redW[2][sabs] + redW[3][sabs];
    comb = bw_loc + gate * (sW / sS);
    if (l4 == 0) out_ew[n*S_ + s0 + sabs] = comb * inv1g;
  }

  // ---- summary: wave w handles s-rows [w*16,+16), comb via in-wave shfl -----
  {
    float4 sacc = {0.f, 0.f, 0.f, 0.f};
    const float* vp = Vn + (size_t)(w*16)*D_ + lane*4;
    #pragma unroll
    for (int j = 0; j < 16; j++){
      float cj = __shfl(comb, j);           // lane j holds row w*16+j (l4==0 copy)
      float4 v = *(const float4*)(vp + (size_t)j*D_);
      sacc.x = fmaf(cj, v.x, sacc.x); sacc.y = fmaf(cj, v.y, sacc.y);
      sacc.z = fmaf(cj, v.z, sacc.z); sacc.w = fmaf(cj, v.w, sacc.w);
    }
    float4* sred = (float4*)KW;             // overlay [4][64] float4 (KW dead)
    sred[w*64 + lane] = sacc;
  }
  __syncthreads();                                   // B5
  if (tid < 64){
    float4 a0 = ((float4*)KW)[tid],       a1 = ((float4*)KW)[64 + tid];
    float4 a2 = ((float4*)KW)[128 + tid], a3 = ((float4*)KW)[192 + tid];
    float* dst = sum_ws + (size_t)n*D_ + tid*4;
    atomicAdd(dst + 0, a0.x + a1.x + a2.x + a3.x);
    atomicAdd(dst + 1, a0.y + a1.y + a2.y + a3.y);
    atomicAdd(dst + 2, a0.z + a1.z + a2.z + a3.z);
    atomicAdd(dst + 3, a0.w + a1.w + a2.w + a3.w);
  }
}

// ---------------- K3: readout GEMM (MFMA, bf16) --------------------------------
__global__ __launch_bounds__(256) void k3(const float* __restrict__ sum_ws,
    const ushortT* __restrict__ Wcr_bf, const float* __restrict__ bc,
    const float* __restrict__ br, float* __restrict__ out)
{
  __shared__ __align__(16) ushortT Stile[64*256];   // 32 KB swizzled bf16 summary tile
  int bx = blockIdx.x;
  int ot = bx >> 4;           // 0..19 output tile (64 wide over [Wc;Wr;pad])
  int nt = bx & 15;           // 0..15 n tile (64 rows)
  int tid = threadIdx.x;
  int lane = tid & 63, wid = tid >> 6;
  int l15 = lane & 15, l4 = lane >> 4;

  const float* Sp = sum_ws + (size_t)nt*64*D_;
  #pragma unroll
  for (int j = 0; j < 8; j++){
    int ch = tid + j*256;
    int row = ch >> 5, blk = ch & 31;
    const float* src = Sp + row*D_ + blk*8;
    float4 a = *(const float4*)src;
    float4 b = *(const float4*)(src + 4);
    uint4 wv = {packbf(a.x,a.y), packbf(a.z,a.w), packbf(b.x,b.y), packbf(b.z,b.w)};
    *(uint4*)((char*)Stile + swz(row, blk*16)) = wv;
  }
  __syncthreads();

  int o0 = ot*64 + wid*16;
  const ushortT* Ap = Wcr_bf + (size_t)(o0 + l15)*D_ + l4*8;
  f4 acc[4];
  #pragma unroll
  for (int j = 0; j < 4; j++) acc[j] = (f4)0.f;
  #pragma unroll
  for (int k = 0; k < 8; k++){
    bf8 a = *(const bf8*)(Ap + k*32);
    #pragma unroll
    for (int nj = 0; nj < 4; nj++){
      bf8 b = *(const bf8*)((const char*)Stile + swz(nj*16 + l15, k*64 + l4*16));
      acc[nj] = __builtin_amdgcn_mfma_f32_16x16x32_bf16(a, b, acc[nj], 0, 0, 0);
    }
  }
  int obase = o0 + l4*4;
  if (obase < 1256){
    float4 bias;
    if (obase < CLS_) bias = *(const float4*)(bc + obase);
    else              bias = *(const float4*)(br + (obase - CLS_));
    #pragma unroll
    for (int nj = 0; nj < 4; nj++){
      int nn = nt*64 + nj*16 + l15;
      float4 v = {acc[nj][0]+bias.x, acc[nj][1]+bias.y, acc[nj][2]+bias.z, acc[nj][3]+bias.w};
      if (obase < CLS_) *(float4*)(out + (size_t)nn*CLS_ + obase) = v;
      else              *(float4*)(out + (size_t)N_*CLS_ + (size_t)nn*D_ + (obase - CLS_)) = v;
    }
  }
}

extern "C" void kernel_launch(void* const* d_in, const int* in_sizes, int n_in,
                              void* d_out, int out_size, void* d_ws, size_t ws_size,
                              hipStream_t stream)
{
  const float* q    = (const float*)d_in[0];
  const float* Kt   = (const float*)d_in[1];
  const float* Vt   = (const float*)d_in[2];
  const float* cb   = (const float*)d_in[3];
  const float* rcb  = (const float*)d_in[4];
  const float* Wq   = (const float*)d_in[5];
  const float* rlg  = (const float*)d_in[6];
  const float* Wc   = (const float*)d_in[7];
  const float* bc   = (const float*)d_in[8];
  const float* Wr   = (const float*)d_in[9];
  const float* br   = (const float*)d_in[10];
  float* out = (float*)d_out;
  float* ws  = (float*)d_ws;

  float* cw_ws  = ws;                          // N*C floats
  float* rcw_ws = ws + 262144;                 // N*R
  float* sum_ws = ws + 327680;                 // N*D
  float* MT_f32 = ws + 589824;                 // R*C
  ushortT* a1pk   = (ushortT*)(ws + 606208);   // 320*D frag-packed
  ushortT* mtpk   = a1pk + (C_ + R_)*D_;       // R*C frag-packed
  ushortT* Wcr_bf = mtpk + R_*C_;              // 1280*D (Wc ; Wr ; zero pad)

  float* out_logits = out;
  float* out_ew     = out + (size_t)N_*CLS_ + (size_t)N_*D_;

  hipMemsetAsync(sum_ws, 0, (size_t)N_*D_*sizeof(float), stream);
  k0 <<<128,  256, 0, stream>>>(cb, rcb, Wc, Wr, a1pk, Wcr_bf);
  k0m<<<R_,   256, 0, stream>>>(cb, rcb, MT_f32, mtpk);
  k1 <<<N_,   256, 0, stream>>>(q, cb, rcb, Wq, MT_f32, cw_ws, rcw_ws);
  k2 <<<N_*4, 256, 0, stream>>>(Kt, Vt, a1pk, mtpk, cw_ws, rcw_ws, rlg,
                                sum_ws, out_ew);
  k3 <<<320,  256, 0, stream>>>(sum_ws, Wcr_bf, bc, br, out_logits);
}